// Round 10
// baseline (2749.346 us; speedup 1.0000x reference)
//
#include <hip/hip_runtime.h>
#include <hip/hip_bf16.h>
#include <math.h>

#define B 256
#define S 128
#define I_DIM 512
#define H 1024
#define C 10
#define WROW 1536

#define LDS_MAIN 131200              // 2 x 64KB B-tiles + counters

typedef float f32x4 __attribute__((ext_vector_type(4), may_alias));
typedef __bf16 bf16x8 __attribute__((ext_vector_type(8), may_alias));
typedef unsigned int u32x4 __attribute__((ext_vector_type(4), may_alias));
typedef unsigned long long u64;

__device__ __forceinline__ unsigned short f2bf(float f) {
    union { float f; unsigned u; } a; a.f = f;
    return (unsigned short)((a.u + 0x7fffu + ((a.u >> 16) & 1u)) >> 16);
}
__device__ __forceinline__ float bf2f(unsigned short b) {
    union { unsigned u; float f; } a; a.u = ((unsigned)b) << 16;
    return a.f;
}
__device__ __forceinline__ float sigf(float v) { return 1.0f / (1.0f + __expf(-v)); }
__device__ __forceinline__ float tanh_fast(float v) { return 1.0f - 2.0f / (1.0f + __expf(2.0f * v)); }

// ---- prep 1a: recurrent W -> bf16 MFMA-fragment stream (k = 512..1535) ----
__global__ void wf_build(const float* __restrict__ fwd_W,
                         const float* __restrict__ bwd_W,
                         __hip_bfloat16* __restrict__ wF) {
    int gid = blockIdx.x * 256 + threadIdx.x;   // 2*256*32*64
    int lane = gid & 63, kk = (gid >> 6) & 31, nsub = (gid >> 11) & 255, d = gid >> 19;
    int n_gl = nsub * 16 + (lane & 15);
    int j = n_gl >> 2, g = n_gl & 3;
    int k = kk * 32 + (lane >> 4) * 8;
    const float* W = d ? bwd_W : fwd_W;
    const float* src = W + (size_t)(g * 1024 + j) * WROW + I_DIM + k;
    ushort4 lo = make_ushort4(f2bf(src[0]), f2bf(src[1]), f2bf(src[2]), f2bf(src[3]));
    ushort4 hi = make_ushort4(f2bf(src[4]), f2bf(src[5]), f2bf(src[6]), f2bf(src[7]));
    ushort4* dst = (ushort4*)(wF + (size_t)gid * 8);
    dst[0] = lo; dst[1] = hi;
}

// ---- prep 1b: input-projection W -> bf16 fragment stream (k = 0..511) ----
__global__ void wxf_build(const float* __restrict__ fwd_W,
                          const float* __restrict__ bwd_W,
                          __hip_bfloat16* __restrict__ wxF) {
    int gid = blockIdx.x * 256 + threadIdx.x;   // 2*256*16*64 = 524288
    int lane = gid & 63, kk = (gid >> 6) & 15, nsub = (gid >> 10) & 255, d = gid >> 18;
    int n_gl = nsub * 16 + (lane & 15);
    int j = n_gl >> 2, g = n_gl & 3;
    int k = kk * 32 + (lane >> 4) * 8;
    const float* W = d ? bwd_W : fwd_W;
    const float* src = W + (size_t)(g * 1024 + j) * WROW + k;
    ushort4 lo = make_ushort4(f2bf(src[0]), f2bf(src[1]), f2bf(src[2]), f2bf(src[3]));
    ushort4 hi = make_ushort4(f2bf(src[4]), f2bf(src[5]), f2bf(src[6]), f2bf(src[7]));
    ushort4* dst = (ushort4*)(wxF + (size_t)gid * 8);
    dst[0] = lo; dst[1] = hi;
}

// ---- prep 1c: embed -> split bf16 (hi + lo, exact to 2^-17) ----
__global__ void ehl_build(const float* __restrict__ embed,
                          unsigned short* __restrict__ ehl) {
    int idx = blockIdx.x * 256 + threadIdx.x;   // 65536
    float e = embed[idx];
    unsigned short hb = f2bf(e);
    unsigned short lb = f2bf(e - bf2f(hb));
    ehl[idx] = hb;
    ehl[65536 + idx] = lb;
}

// ---- prep 2: projP[d][j][v][g] via split-bf16 MFMA (f32-accurate) ----
// 256 blocks = (d, jt(32), vb(4)); 256 thr (4 waves); wave: 32n x 32v, K=512.
__global__ __launch_bounds__(256) void projp_mfma(
        const __hip_bfloat16* __restrict__ wxF,
        const unsigned short* __restrict__ ehl,
        const float* __restrict__ fwd_b,
        const float* __restrict__ bwd_b,
        float* __restrict__ projP) {
    extern __shared__ char sm[];
    const int bid = blockIdx.x;
    const int d = bid >> 7, jt = (bid >> 2) & 31, vb = bid & 3;
    const int tid = threadIdx.x, w = tid >> 6, lane = tid & 63;
    const int l15 = lane & 15, l4 = lane >> 4;
    const int v0 = vb * 32;

    // stage ehl: rows 0..31 = hi(v0..v0+31), rows 32..63 = lo; 1024B rows, swizzled
    for (int i = 0; i < 16; i++) {
        int chunk = i * 256 + tid;
        int row = chunk >> 6, c16 = chunk & 63;
        int p = row >> 5, vs = v0 + (row & 31);
        u32x4 vd = *(const u32x4*)(ehl + ((size_t)p * 128 + vs) * 512 + c16 * 8);
        *(u32x4*)(sm + row * 1024 + ((c16 * 16) ^ ((row & 7) << 4))) = vd;
    }
    __syncthreads();

    const __hip_bfloat16* ap0 = wxF + ((size_t)((d * 256 + jt * 8 + w * 2 + 0) * 16)) * 512;
    const __hip_bfloat16* ap1 = wxF + ((size_t)((d * 256 + jt * 8 + w * 2 + 1) * 16)) * 512;
    int hrow[2], hswz[2], lrow[2], lswz[2];
#pragma unroll
    for (int vt = 0; vt < 2; vt++) {
        int hr = vt * 16 + l15, lr = hr + 32;
        hrow[vt] = hr * 1024; hswz[vt] = (hr & 7) << 4;
        lrow[vt] = lr * 1024; lswz[vt] = (lr & 7) << 4;
    }
    f32x4 acc[2][2] = {};
#pragma unroll
    for (int kk = 0; kk < 16; kk++) {
        bf16x8 A0 = *(const bf16x8*)(ap0 + kk * 512 + lane * 8);
        bf16x8 A1 = *(const bf16x8*)(ap1 + kk * 512 + lane * 8);
        int ko = kk * 64 + l4 * 16;
        bf16x8 Bh0 = *(const bf16x8*)(sm + hrow[0] + (ko ^ hswz[0]));
        bf16x8 Bh1 = *(const bf16x8*)(sm + hrow[1] + (ko ^ hswz[1]));
        bf16x8 Bl0 = *(const bf16x8*)(sm + lrow[0] + (ko ^ lswz[0]));
        bf16x8 Bl1 = *(const bf16x8*)(sm + lrow[1] + (ko ^ lswz[1]));
        acc[0][0] = __builtin_amdgcn_mfma_f32_16x16x32_bf16(A0, Bh0, acc[0][0], 0, 0, 0);
        acc[0][0] = __builtin_amdgcn_mfma_f32_16x16x32_bf16(A0, Bl0, acc[0][0], 0, 0, 0);
        acc[0][1] = __builtin_amdgcn_mfma_f32_16x16x32_bf16(A0, Bh1, acc[0][1], 0, 0, 0);
        acc[0][1] = __builtin_amdgcn_mfma_f32_16x16x32_bf16(A0, Bl1, acc[0][1], 0, 0, 0);
        acc[1][0] = __builtin_amdgcn_mfma_f32_16x16x32_bf16(A1, Bh0, acc[1][0], 0, 0, 0);
        acc[1][0] = __builtin_amdgcn_mfma_f32_16x16x32_bf16(A1, Bl0, acc[1][0], 0, 0, 0);
        acc[1][1] = __builtin_amdgcn_mfma_f32_16x16x32_bf16(A1, Bh1, acc[1][1], 0, 0, 0);
        acc[1][1] = __builtin_amdgcn_mfma_f32_16x16x32_bf16(A1, Bl1, acc[1][1], 0, 0, 0);
    }
    const float* bp = d ? bwd_b : fwd_b;
#pragma unroll
    for (int nt = 0; nt < 2; nt++) {
        int j = jt * 32 + w * 8 + nt * 4 + l4;
        f32x4 bv = { bp[j], bp[1024 + j], bp[2048 + j], bp[3072 + j] };
#pragma unroll
        for (int vt = 0; vt < 2; vt++) {
            int v = v0 + vt * 16 + l15;
            *(f32x4*)(projP + ((size_t)(d * 1024 + j) * 128 + v) * 4) = acc[nt][vt] + bv;
        }
    }
}

// stage 8 x 16B h chunks (L3-coherent sc0 sc1) into swizzled LDS; rows ibase+2q+r0
__device__ __forceinline__ void stage_batch(const __hip_bfloat16* hr, char* dst,
                                            int r0, int cc, int ibase) {
    const void* p0 = (const void*)(hr + (size_t)(ibase + 0 + r0) * H + cc * 8);
    const void* p1 = (const void*)(hr + (size_t)(ibase + 2 + r0) * H + cc * 8);
    const void* p2 = (const void*)(hr + (size_t)(ibase + 4 + r0) * H + cc * 8);
    const void* p3 = (const void*)(hr + (size_t)(ibase + 6 + r0) * H + cc * 8);
    const void* p4 = (const void*)(hr + (size_t)(ibase + 8 + r0) * H + cc * 8);
    const void* p5 = (const void*)(hr + (size_t)(ibase + 10 + r0) * H + cc * 8);
    const void* p6 = (const void*)(hr + (size_t)(ibase + 12 + r0) * H + cc * 8);
    const void* p7 = (const void*)(hr + (size_t)(ibase + 14 + r0) * H + cc * 8);
    u32x4 s0, s1, s2, s3, s4, s5, s6, s7;
    asm volatile(
        "global_load_dwordx4 %0, %8, off sc0 sc1\n\t"
        "global_load_dwordx4 %1, %9, off sc0 sc1\n\t"
        "global_load_dwordx4 %2, %10, off sc0 sc1\n\t"
        "global_load_dwordx4 %3, %11, off sc0 sc1\n\t"
        "global_load_dwordx4 %4, %12, off sc0 sc1\n\t"
        "global_load_dwordx4 %5, %13, off sc0 sc1\n\t"
        "global_load_dwordx4 %6, %14, off sc0 sc1\n\t"
        "global_load_dwordx4 %7, %15, off sc0 sc1\n\t"
        "s_waitcnt vmcnt(0)"
        : "=&v"(s0), "=&v"(s1), "=&v"(s2), "=&v"(s3),
          "=&v"(s4), "=&v"(s5), "=&v"(s6), "=&v"(s7)
        : "v"(p0), "v"(p1), "v"(p2), "v"(p3), "v"(p4), "v"(p5), "v"(p6), "v"(p7)
        : "memory");
    int row;
    row = ibase + 0 + r0;  *(u32x4*)(dst + row * 2048 + ((cc * 16) ^ ((row & 7) << 4))) = s0;
    row = ibase + 2 + r0;  *(u32x4*)(dst + row * 2048 + ((cc * 16) ^ ((row & 7) << 4))) = s1;
    row = ibase + 4 + r0;  *(u32x4*)(dst + row * 2048 + ((cc * 16) ^ ((row & 7) << 4))) = s2;
    row = ibase + 6 + r0;  *(u32x4*)(dst + row * 2048 + ((cc * 16) ^ ((row & 7) << 4))) = s3;
    row = ibase + 8 + r0;  *(u32x4*)(dst + row * 2048 + ((cc * 16) ^ ((row & 7) << 4))) = s4;
    row = ibase + 10 + r0; *(u32x4*)(dst + row * 2048 + ((cc * 16) ^ ((row & 7) << 4))) = s5;
    row = ibase + 12 + r0; *(u32x4*)(dst + row * 2048 + ((cc * 16) ^ ((row & 7) << 4))) = s6;
    row = ibase + 14 + r0; *(u32x4*)(dst + row * 2048 + ((cc * 16) ^ ((row & 7) << 4))) = s7;
}

// ---- persistent dual-direction bi-LSTM ----
// 256 blocks x 512 thr. block=(bt(8), jt(32)): BOTH dirs of 32b x 128n.
// waves 0-3 = fwd group, 4-7 = bwd group; independent flags + LDS barriers;
// NO __syncthreads in the loop -> one group's MFMAs hide the other's sync stall.
__global__ __launch_bounds__(512, 2) void bilstm_persistent(
        const int* __restrict__ x,
        const __hip_bfloat16* __restrict__ wF,
        const float* __restrict__ projP,
        __hip_bfloat16* __restrict__ hbuf,   // [2 parity][2 d][256 b][1024 j]
        unsigned* __restrict__ flags) {      // [2 d][8 bt] stride-16 u32, monotonic
    extern __shared__ char smem[];
    unsigned* cnt = (unsigned*)(smem + 131072);  // [0..1] store-arrive, [2..3] stage-bar
    const int bid = blockIdx.x;
    const int bt = bid >> 5, jt = bid & 31;      // XCD = jt&7: bt-sharers co-XCD
    const int tid = threadIdx.x;
    const int d = tid >> 8;                      // direction group
    const int tid2 = tid & 255;
    const int w = tid2 >> 6, lane = tid & 63;
    const int l15 = lane & 15, l4 = lane >> 4;
    const int b0 = bt * 32;
    const size_t dBH = (size_t)d * B * H;
    char* btile = smem + d * 65536;

    if (tid < 4) cnt[tid] = 0;
    __syncthreads();   // once, before the loop

    const __hip_bfloat16* wp = wF + ((size_t)((d * 256 + jt * 8 + w * 2) * 32)) * 512;
    int brow[2], bswz[2];
#pragma unroll
    for (int bs = 0; bs < 2; bs++) {
        int row = bs * 16 + l15;
        brow[bs] = row * 2048;
        bswz[bs] = (row & 7) << 4;
    }
    const int jbase = jt * 32 + w * 8;
    const int r0 = tid2 >> 7, cc = tid2 & 127;
    unsigned* flagp = flags + (size_t)(d * 8 + bt) * 16;

    float cst[2][2] = {};
    int vv[2];
    f32x4 pj[2][2];
    {   // prefetch x/proj for t=0
        int tt = d ? (S - 1) : 0;
        vv[0] = x[(b0 + l15) * S + tt];
        vv[1] = x[(b0 + 16 + l15) * S + tt];
#pragma unroll
        for (int nt = 0; nt < 2; nt++) {
            int j = jbase + nt * 4 + l4;
            const float* pb = projP + (size_t)(d * 1024 + j) * 128 * 4;
            pj[nt][0] = *(const f32x4*)(pb + vv[0] * 4);
            pj[nt][1] = *(const f32x4*)(pb + vv[1] * 4);
        }
    }

    for (int t = 0; t < S; t++) {
        bf16x8 Ap[2][4];
        if (t > 0) {
#pragma unroll
            for (int p = 0; p < 4; p++) {   // A-ring preload (L2-hot, before poll)
                Ap[0][p] = *(const bf16x8*)(wp + (0 * 32 + p) * 512 + lane * 8);
                Ap[1][p] = *(const bf16x8*)(wp + (1 * 32 + p) * 512 + lane * 8);
            }
            // poll: producers' step t-1 complete (subsumes own group's store-drain)
            if (lane == 0) {
                while (__hip_atomic_load(flagp, __ATOMIC_RELAXED,
                                         __HIP_MEMORY_SCOPE_AGENT) < 32u * (unsigned)t)
                    __builtin_amdgcn_s_sleep(2);
            }
            asm volatile("" ::: "memory");
            const __hip_bfloat16* hr = hbuf + (size_t)(t & 1) * 2 * B * H + dBH + (size_t)b0 * H;
            stage_batch(hr, btile, r0, cc, 0);
            stage_batch(hr, btile, r0, cc, 16);
            // dir-group stage barrier (4 waves), monotonic LDS counter
            if (lane == 0)
                __hip_atomic_fetch_add(&cnt[2 + d], 1u, __ATOMIC_RELAXED,
                                       __HIP_MEMORY_SCOPE_WORKGROUP);
            while (__hip_atomic_load(&cnt[2 + d], __ATOMIC_RELAXED,
                                     __HIP_MEMORY_SCOPE_WORKGROUP) < 4u * (unsigned)t)
                __builtin_amdgcn_s_sleep(1);
            asm volatile("" ::: "memory");
        }

        f32x4 acc[2][2] = {};
        if (t > 0) {
            bf16x8 Bc0 = *(const bf16x8*)(btile + brow[0] + ((l4 * 16) ^ bswz[0]));
            bf16x8 Bc1 = *(const bf16x8*)(btile + brow[1] + ((l4 * 16) ^ bswz[1]));
#pragma unroll
            for (int kk = 0; kk < 32; kk++) {
                bf16x8 A0 = Ap[0][kk & 3], A1 = Ap[1][kk & 3];
                bf16x8 B0 = Bc0, B1 = Bc1;
                if (kk < 28) {
                    Ap[0][kk & 3] = *(const bf16x8*)(wp + (0 * 32 + kk + 4) * 512 + lane * 8);
                    Ap[1][kk & 3] = *(const bf16x8*)(wp + (1 * 32 + kk + 4) * 512 + lane * 8);
                }
                if (kk < 31) {
                    int koff = (kk + 1) * 64 + l4 * 16;
                    Bc0 = *(const bf16x8*)(btile + brow[0] + (koff ^ bswz[0]));
                    Bc1 = *(const bf16x8*)(btile + brow[1] + (koff ^ bswz[1]));
                }
                acc[0][0] = __builtin_amdgcn_mfma_f32_16x16x32_bf16(A0, B0, acc[0][0], 0, 0, 0);
                acc[0][1] = __builtin_amdgcn_mfma_f32_16x16x32_bf16(A0, B1, acc[0][1], 0, 0, 0);
                acc[1][0] = __builtin_amdgcn_mfma_f32_16x16x32_bf16(A1, B0, acc[1][0], 0, 0, 0);
                acc[1][1] = __builtin_amdgcn_mfma_f32_16x16x32_bf16(A1, B1, acc[1][1], 0, 0, 0);
            }
        }

        // gates: lane owns (j = jbase + nt*4 + l4, b = b0 + bs*16 + l15); g in regs
        float hn[2][2];
#pragma unroll
        for (int nt = 0; nt < 2; nt++)
#pragma unroll
            for (int bs = 0; bs < 2; bs++) {
                float zg = acc[nt][bs][0] + pj[nt][bs][0];
                float zi = acc[nt][bs][1] + pj[nt][bs][1];
                float zf = acc[nt][bs][2] + pj[nt][bs][2];
                float zo = acc[nt][bs][3] + pj[nt][bs][3];
                float gg = tanh_fast(zg);
                float ii = sigf(zi);
                float ff = sigf(zf);
                float oo = sigf(zo);
                float cn = gg * ii + cst[nt][bs] * ff;
                cst[nt][bs] = cn;
                hn[nt][bs] = tanh_fast(cn) * oo;
            }

        // register shfl transpose -> 16B coherent store (lanes 0..31 = 32 b-rows)
        unsigned pk0 = (unsigned)f2bf(hn[0][0]) | ((unsigned)f2bf(hn[0][1]) << 16);
        unsigned pk1 = (unsigned)f2bf(hn[1][0]) | ((unsigned)f2bf(hn[1][1]) << 16);
        unsigned sv[8];
#pragma unroll
        for (int q = 0; q < 8; q++) {
            unsigned pk = (q < 4) ? pk0 : pk1;
            unsigned s = __shfl(pk, (q & 3) * 16 + l15);
            sv[q] = (lane & 16) ? (s >> 16) : (s & 0xffffu);
        }
        if (lane < 32) {
            u32x4 hv = { sv[0] | (sv[1] << 16), sv[2] | (sv[3] << 16),
                         sv[4] | (sv[5] << 16), sv[6] | (sv[7] << 16) };
            void* hw = (void*)(hbuf + (size_t)((t + 1) & 1) * 2 * B * H + dBH
                               + (size_t)(b0 + lane) * H + jbase);
            asm volatile("global_store_dwordx4 %0, %1, off sc0 sc1"
                         :: "v"(hw), "v"(hv) : "memory");
        }
        asm volatile("s_waitcnt vmcnt(0)" ::: "memory");
        if (lane == 0) {
            unsigned old = __hip_atomic_fetch_add(&cnt[d], 1u, __ATOMIC_RELAXED,
                                                  __HIP_MEMORY_SCOPE_WORKGROUP);
            if (old == 4u * (unsigned)t + 3u)
                __hip_atomic_fetch_add(flagp, 1u, __ATOMIC_RELAXED,
                                       __HIP_MEMORY_SCOPE_AGENT);
        }

        // prefetch x/proj for t+1 (overlaps next poll)
        if (t + 1 < S) {
            int tt = d ? (S - 2 - t) : (t + 1);
            vv[0] = x[(b0 + l15) * S + tt];
            vv[1] = x[(b0 + 16 + l15) * S + tt];
#pragma unroll
            for (int nt = 0; nt < 2; nt++) {
                int j = jbase + nt * 4 + l4;
                const float* pb = projP + (size_t)(d * 1024 + j) * 128 * 4;
                pj[nt][0] = *(const f32x4*)(pb + vv[0] * 4);
                pj[nt][1] = *(const f32x4*)(pb + vv[1] * 4);
            }
        }
    }
}

// ---- head: logits + log_softmax (reads bf16 h, parity 0) ----
__global__ void head_kernel(const __hip_bfloat16* __restrict__ hbuf,
                            const float* __restrict__ p_w,
                            const float* __restrict__ p_b,
                            float* __restrict__ out) {
    int b = blockIdx.x;
    int lane = threadIdx.x;  // 64
    float part[C];
#pragma unroll
    for (int cc2 = 0; cc2 < C; cc2++) part[cc2] = 0.0f;
    for (int jj = lane; jj < 2 * H; jj += 64) {
        float hv = (jj < H)
            ? __bfloat162float(hbuf[(size_t)b * H + jj])
            : __bfloat162float(hbuf[(size_t)B * H + (size_t)b * H + jj - H]);
#pragma unroll
        for (int cc2 = 0; cc2 < C; cc2++) part[cc2] += hv * p_w[cc2 * 2 * H + jj];
    }
#pragma unroll
    for (int cc2 = 0; cc2 < C; cc2++) {
        float v = part[cc2];
        for (int off = 32; off; off >>= 1) v += __shfl_down(v, off);
        part[cc2] = v;
    }
    if (lane == 0) {
        float lg[C];
        float m = -1e30f;
        for (int cc2 = 0; cc2 < C; cc2++) {
            lg[cc2] = part[cc2] + p_b[cc2];
            m = fmaxf(m, lg[cc2]);
        }
        float s = 0.0f;
        for (int cc2 = 0; cc2 < C; cc2++) s += expf(lg[cc2] - m);
        float lse = logf(s) + m;
        for (int cc2 = 0; cc2 < C; cc2++) out[b * C + cc2] = lg[cc2] - lse;
    }
}

extern "C" void kernel_launch(void* const* d_in, const int* in_sizes, int n_in,
                              void* d_out, int out_size, void* d_ws, size_t ws_size,
                              hipStream_t stream) {
    const int*   x     = (const int*)d_in[0];
    const float* embed = (const float*)d_in[1];
    const float* fwd_W = (const float*)d_in[2];
    const float* fwd_b = (const float*)d_in[3];
    const float* bwd_W = (const float*)d_in[4];
    const float* bwd_b = (const float*)d_in[5];
    const float* p_w   = (const float*)d_in[6];
    const float* p_b   = (const float*)d_in[7];
    float* outp = (float*)d_out;

    char* ws = (char*)d_ws;
    __hip_bfloat16* wF  = (__hip_bfloat16*)ws;  ws += (size_t)2 * 256 * 16384 * 2;    // 16 MB
    __hip_bfloat16* wxF = (__hip_bfloat16*)ws;  ws += (size_t)2 * 256 * 8192 * 2;     // 8 MB
    unsigned short* ehl = (unsigned short*)ws;  ws += (size_t)2 * 128 * 512 * 2;      // 256 KB
    float* projP = (float*)ws;                  ws += (size_t)2 * 1024 * 128 * 4 * 4; // 4 MB
    __hip_bfloat16* hbuf = (__hip_bfloat16*)ws; ws += (size_t)2 * 2 * B * H * 2;      // 2 MB
    unsigned* flags = (unsigned*)ws;            ws += (size_t)2 * 8 * 16 * 4;         // 1 KB

    hipMemsetAsync(flags, 0, (size_t)2 * 8 * 16 * 4, stream);
    hipLaunchKernelGGL(wf_build, dim3(4096), dim3(256), 0, stream, fwd_W, bwd_W, wF);
    hipLaunchKernelGGL(wxf_build, dim3(2048), dim3(256), 0, stream, fwd_W, bwd_W, wxF);
    hipLaunchKernelGGL(ehl_build, dim3(256), dim3(256), 0, stream, embed, ehl);

    hipFuncSetAttribute((const void*)projp_mfma,
                        hipFuncAttributeMaxDynamicSharedMemorySize, 65536);
    hipLaunchKernelGGL(projp_mfma, dim3(256), dim3(256), 65536, stream,
                       wxF, ehl, fwd_b, bwd_b, projP);

    hipFuncSetAttribute((const void*)bilstm_persistent,
                        hipFuncAttributeMaxDynamicSharedMemorySize, LDS_MAIN);
    void* args[] = {(void*)&x, (void*)&wF, (void*)&projP, (void*)&hbuf, (void*)&flags};
    hipLaunchCooperativeKernel((void*)bilstm_persistent, dim3(256), dim3(512),
                               args, LDS_MAIN, stream);

    hipLaunchKernelGGL(head_kernel, dim3(B), dim3(64), 0, stream,
                       hbuf, p_w, p_b, outp);
}

// Round 11
// 1647.522 us; speedup vs baseline: 1.6688x; 1.6688x over previous
//
#include <hip/hip_runtime.h>
#include <hip/hip_bf16.h>
#include <math.h>

#define B 256
#define S 128
#define I_DIM 512
#define H 1024
#define C 10
#define WROW 1536

#define LDS_H 131072                 // 64 b-rows x 1024 k bf16, XOR-swizzled

typedef float f32x4 __attribute__((ext_vector_type(4), may_alias));
typedef __bf16 bf16x8 __attribute__((ext_vector_type(8), may_alias));
typedef unsigned int u32x4 __attribute__((ext_vector_type(4), may_alias));
typedef unsigned long long u64;
typedef unsigned long long __attribute__((may_alias)) u64a;

__device__ __forceinline__ unsigned short f2bf(float f) {
    union { float f; unsigned u; } a; a.f = f;
    return (unsigned short)((a.u + 0x7fffu + ((a.u >> 16) & 1u)) >> 16);
}
__device__ __forceinline__ float bf2f(unsigned short b) {
    union { unsigned u; float f; } a; a.u = ((unsigned)b) << 16;
    return a.f;
}
__device__ __forceinline__ float sigf(float v) { return 1.0f / (1.0f + __expf(-v)); }
__device__ __forceinline__ float tanh_fast(float v) { return 1.0f - 2.0f / (1.0f + __expf(2.0f * v)); }

// ---- prep 1a: recurrent W -> bf16 MFMA-fragment stream (k = 512..1535) ----
__global__ void wf_build(const float* __restrict__ fwd_W,
                         const float* __restrict__ bwd_W,
                         __hip_bfloat16* __restrict__ wF) {
    int gid = blockIdx.x * 256 + threadIdx.x;   // 2*256*32*64
    int lane = gid & 63, kk = (gid >> 6) & 31, nsub = (gid >> 11) & 255, d = gid >> 19;
    int n_gl = nsub * 16 + (lane & 15);
    int j = n_gl >> 2, g = n_gl & 3;
    int k = kk * 32 + (lane >> 4) * 8;
    const float* W = d ? bwd_W : fwd_W;
    const float* src = W + (size_t)(g * 1024 + j) * WROW + I_DIM + k;
    ushort4 lo = make_ushort4(f2bf(src[0]), f2bf(src[1]), f2bf(src[2]), f2bf(src[3]));
    ushort4 hi = make_ushort4(f2bf(src[4]), f2bf(src[5]), f2bf(src[6]), f2bf(src[7]));
    ushort4* dst = (ushort4*)(wF + (size_t)gid * 8);
    dst[0] = lo; dst[1] = hi;
}

// ---- prep 1b: input-projection W -> bf16 fragment stream (k = 0..511) ----
__global__ void wxf_build(const float* __restrict__ fwd_W,
                          const float* __restrict__ bwd_W,
                          __hip_bfloat16* __restrict__ wxF) {
    int gid = blockIdx.x * 256 + threadIdx.x;   // 2*256*16*64 = 524288
    int lane = gid & 63, kk = (gid >> 6) & 15, nsub = (gid >> 10) & 255, d = gid >> 18;
    int n_gl = nsub * 16 + (lane & 15);
    int j = n_gl >> 2, g = n_gl & 3;
    int k = kk * 32 + (lane >> 4) * 8;
    const float* W = d ? bwd_W : fwd_W;
    const float* src = W + (size_t)(g * 1024 + j) * WROW + k;
    ushort4 lo = make_ushort4(f2bf(src[0]), f2bf(src[1]), f2bf(src[2]), f2bf(src[3]));
    ushort4 hi = make_ushort4(f2bf(src[4]), f2bf(src[5]), f2bf(src[6]), f2bf(src[7]));
    ushort4* dst = (ushort4*)(wxF + (size_t)gid * 8);
    dst[0] = lo; dst[1] = hi;
}

// ---- prep 1c: embed -> split bf16 (hi + lo, exact to 2^-17) ----
__global__ void ehl_build(const float* __restrict__ embed,
                          unsigned short* __restrict__ ehl) {
    int idx = blockIdx.x * 256 + threadIdx.x;   // 65536
    float e = embed[idx];
    unsigned short hb = f2bf(e);
    unsigned short lb = f2bf(e - bf2f(hb));
    ehl[idx] = hb;
    ehl[65536 + idx] = lb;
}

// ---- prep 2: projP[d][j][v][g] via split-bf16 MFMA (f32-accurate) ----
// 256 blocks = (d, jt(32), vb(4)); 256 thr (4 waves); wave: 32n x 32v, K=512.
// Verified correct in round 10 (absmax unchanged).
__global__ __launch_bounds__(256) void projp_mfma(
        const __hip_bfloat16* __restrict__ wxF,
        const unsigned short* __restrict__ ehl,
        const float* __restrict__ fwd_b,
        const float* __restrict__ bwd_b,
        float* __restrict__ projP) {
    extern __shared__ char sm[];
    const int bid = blockIdx.x;
    const int d = bid >> 7, jt = (bid >> 2) & 31, vb = bid & 3;
    const int tid = threadIdx.x, w = tid >> 6, lane = tid & 63;
    const int l15 = lane & 15, l4 = lane >> 4;
    const int v0 = vb * 32;

    for (int i = 0; i < 16; i++) {
        int chunk = i * 256 + tid;
        int row = chunk >> 6, c16 = chunk & 63;
        int p = row >> 5, vs = v0 + (row & 31);
        u32x4 vd = *(const u32x4*)(ehl + ((size_t)p * 128 + vs) * 512 + c16 * 8);
        *(u32x4*)(sm + row * 1024 + ((c16 * 16) ^ ((row & 7) << 4))) = vd;
    }
    __syncthreads();

    const __hip_bfloat16* ap0 = wxF + ((size_t)((d * 256 + jt * 8 + w * 2 + 0) * 16)) * 512;
    const __hip_bfloat16* ap1 = wxF + ((size_t)((d * 256 + jt * 8 + w * 2 + 1) * 16)) * 512;
    int hrow[2], hswz[2], lrow[2], lswz[2];
#pragma unroll
    for (int vt = 0; vt < 2; vt++) {
        int hr = vt * 16 + l15, lr = hr + 32;
        hrow[vt] = hr * 1024; hswz[vt] = (hr & 7) << 4;
        lrow[vt] = lr * 1024; lswz[vt] = (lr & 7) << 4;
    }
    f32x4 acc[2][2] = {};
#pragma unroll
    for (int kk = 0; kk < 16; kk++) {
        bf16x8 A0 = *(const bf16x8*)(ap0 + kk * 512 + lane * 8);
        bf16x8 A1 = *(const bf16x8*)(ap1 + kk * 512 + lane * 8);
        int ko = kk * 64 + l4 * 16;
        bf16x8 Bh0 = *(const bf16x8*)(sm + hrow[0] + (ko ^ hswz[0]));
        bf16x8 Bh1 = *(const bf16x8*)(sm + hrow[1] + (ko ^ hswz[1]));
        bf16x8 Bl0 = *(const bf16x8*)(sm + lrow[0] + (ko ^ lswz[0]));
        bf16x8 Bl1 = *(const bf16x8*)(sm + lrow[1] + (ko ^ lswz[1]));
        acc[0][0] = __builtin_amdgcn_mfma_f32_16x16x32_bf16(A0, Bh0, acc[0][0], 0, 0, 0);
        acc[0][0] = __builtin_amdgcn_mfma_f32_16x16x32_bf16(A0, Bl0, acc[0][0], 0, 0, 0);
        acc[0][1] = __builtin_amdgcn_mfma_f32_16x16x32_bf16(A0, Bh1, acc[0][1], 0, 0, 0);
        acc[0][1] = __builtin_amdgcn_mfma_f32_16x16x32_bf16(A0, Bl1, acc[0][1], 0, 0, 0);
        acc[1][0] = __builtin_amdgcn_mfma_f32_16x16x32_bf16(A1, Bh0, acc[1][0], 0, 0, 0);
        acc[1][0] = __builtin_amdgcn_mfma_f32_16x16x32_bf16(A1, Bl0, acc[1][0], 0, 0, 0);
        acc[1][1] = __builtin_amdgcn_mfma_f32_16x16x32_bf16(A1, Bh1, acc[1][1], 0, 0, 0);
        acc[1][1] = __builtin_amdgcn_mfma_f32_16x16x32_bf16(A1, Bl1, acc[1][1], 0, 0, 0);
    }
    const float* bp = d ? bwd_b : fwd_b;
#pragma unroll
    for (int nt = 0; nt < 2; nt++) {
        int j = jt * 32 + w * 8 + nt * 4 + l4;
        f32x4 bv = { bp[j], bp[1024 + j], bp[2048 + j], bp[3072 + j] };
#pragma unroll
        for (int vt = 0; vt < 2; vt++) {
            int v = v0 + vt * 16 + l15;
            *(f32x4*)(projP + ((size_t)(d * 1024 + j) * 128 + v) * 4) = acc[nt][vt] + bv;
        }
    }
}

// ---- fused per-step kernel (r6 chassis + T14 k-halved stage/GEMM pipeline) ----
// grid 256 x 512thr. block=(d, bt, jt): 64 b x 32 j (128 gate-interleaved n).
// 8 waves: wave wid owns j = jt*32 + wid*4 + l4 (16 n) x 64 b.
// Stage: two register batches (k-cols 0..511 / 512..1023, same coalesced map).
// GEMM half1 (kk 0..15) runs while batch2 is in flight; A-ring streams once.
__global__ __launch_bounds__(512, 1) void step_kernel(
        const int* __restrict__ x,
        const __hip_bfloat16* __restrict__ wF,
        const float* __restrict__ projP,
        __hip_bfloat16* __restrict__ hbuf,   // [2 parity][2 d][256 b][1024 j]
        float* __restrict__ cws,             // [256 blk][512 tid][4]
        int t) {
    extern __shared__ char smem[];
    const int bid = blockIdx.x;
    const int d = bid >> 7, bt = (bid >> 5) & 3, jt = bid & 31;
    const int tid = threadIdx.x, wid = tid >> 6, lane = tid & 63;
    const int l15 = lane & 15, l4 = lane >> 4;
    const int b0 = bt * 64;
    const size_t dBH = (size_t)d * B * H;

    const __hip_bfloat16* wp = wF + (size_t)(d * 256 + jt * 8 + wid) * 16384;

    // ---- issue all long-latency loads up front ----
    bf16x8 Ap[8];
    if (t > 0) {
#pragma unroll
        for (int p = 0; p < 8; p++)
            Ap[p] = *(const bf16x8*)(wp + p * 512 + lane * 8);
    }
    const int tt = d ? (S - 1 - t) : t;
    int vv[4];
#pragma unroll
    for (int bs = 0; bs < 4; bs++)
        vv[bs] = x[(b0 + bs * 16 + l15) * S + tt];

    // stage h[d][b0..b0+64][*] into registers: batch1 = k-cols 0..511, batch2 rest
    u32x4 sb1[8], sb2[8];
    int srow[8], sc16[8];
    if (t > 0) {
        const __hip_bfloat16* hr = hbuf + (size_t)(t & 1) * 2 * B * H + dBH + (size_t)b0 * H;
#pragma unroll
        for (int i = 0; i < 8; i++) {
            int flat = i * 512 + tid;        // 0..4095: row = flat>>6, c16 = flat&63
            srow[i] = flat >> 6;
            sc16[i] = flat & 63;
            sb1[i] = *(const u32x4*)(hr + (size_t)srow[i] * H + sc16[i] * 8);
        }
#pragma unroll
        for (int i = 0; i < 8; i++)
            sb2[i] = *(const u32x4*)(hr + (size_t)srow[i] * H + (sc16[i] + 64) * 8);
    }

    // proj gather (vv arrived by now)
    const int j = jt * 32 + wid * 4 + l4;
    const f32x4* pp = (const f32x4*)projP + ((size_t)d * 1024 + j) * 128;
    f32x4 pj[4];
#pragma unroll
    for (int bs = 0; bs < 4; bs++) pj[bs] = pp[vv[bs]];

    float* cp = cws + ((size_t)bid * 512 + tid) * 4;
    f32x4 cv = {0.f, 0.f, 0.f, 0.f};
    if (t > 0) cv = *(const f32x4*)cp;

    f32x4 acc[4] = {};
    if (t > 0) {
        // write batch1 (k-half 0) to swizzled LDS
#pragma unroll
        for (int i = 0; i < 8; i++)
            *(u32x4*)(smem + srow[i] * 2048 + ((sc16[i] * 16) ^ ((srow[i] & 7) << 4))) = sb1[i];
        __syncthreads();

        int brow[4], bswz[4];
#pragma unroll
        for (int bs = 0; bs < 4; bs++) {
            int row = bs * 16 + l15;
            brow[bs] = row * 2048;
            bswz[bs] = (row & 7) << 4;
        }

        // GEMM half 1: kk 0..15 (k-cols 0..511), batch2 still in flight
#pragma unroll
        for (int kk = 0; kk < 16; kk++) {
            bf16x8 A = Ap[kk & 7];
            Ap[kk & 7] = *(const bf16x8*)(wp + (kk + 8) * 512 + lane * 8);
            int koff = kk * 64 + l4 * 16;
            bf16x8 B0 = *(const bf16x8*)(smem + brow[0] + (koff ^ bswz[0]));
            bf16x8 B1 = *(const bf16x8*)(smem + brow[1] + (koff ^ bswz[1]));
            bf16x8 B2 = *(const bf16x8*)(smem + brow[2] + (koff ^ bswz[2]));
            bf16x8 B3 = *(const bf16x8*)(smem + brow[3] + (koff ^ bswz[3]));
            acc[0] = __builtin_amdgcn_mfma_f32_16x16x32_bf16(A, B0, acc[0], 0, 0, 0);
            acc[1] = __builtin_amdgcn_mfma_f32_16x16x32_bf16(A, B1, acc[1], 0, 0, 0);
            acc[2] = __builtin_amdgcn_mfma_f32_16x16x32_bf16(A, B2, acc[2], 0, 0, 0);
            acc[3] = __builtin_amdgcn_mfma_f32_16x16x32_bf16(A, B3, acc[3], 0, 0, 0);
        }

        // write batch2 (k-half 1); compiler inserts the exact vmcnt needed
#pragma unroll
        for (int i = 0; i < 8; i++)
            *(u32x4*)(smem + srow[i] * 2048 + (((sc16[i] + 64) * 16) ^ ((srow[i] & 7) << 4))) = sb2[i];
        __syncthreads();

        // GEMM half 2: kk 16..31
#pragma unroll
        for (int kk = 16; kk < 32; kk++) {
            bf16x8 A = Ap[kk & 7];
            if (kk < 24)
                Ap[kk & 7] = *(const bf16x8*)(wp + (kk + 8) * 512 + lane * 8);
            int koff = kk * 64 + l4 * 16;
            bf16x8 B0 = *(const bf16x8*)(smem + brow[0] + (koff ^ bswz[0]));
            bf16x8 B1 = *(const bf16x8*)(smem + brow[1] + (koff ^ bswz[1]));
            bf16x8 B2 = *(const bf16x8*)(smem + brow[2] + (koff ^ bswz[2]));
            bf16x8 B3 = *(const bf16x8*)(smem + brow[3] + (koff ^ bswz[3]));
            acc[0] = __builtin_amdgcn_mfma_f32_16x16x32_bf16(A, B0, acc[0], 0, 0, 0);
            acc[1] = __builtin_amdgcn_mfma_f32_16x16x32_bf16(A, B1, acc[1], 0, 0, 0);
            acc[2] = __builtin_amdgcn_mfma_f32_16x16x32_bf16(A, B2, acc[2], 0, 0, 0);
            acc[3] = __builtin_amdgcn_mfma_f32_16x16x32_bf16(A, B3, acc[3], 0, 0, 0);
        }
    }

    // gates: lane owns (j, b = b0 + bs*16 + l15); 4 gates in acc[bs][0..3]
    float hnv[4];
#pragma unroll
    for (int bs = 0; bs < 4; bs++) {
        float zg = acc[bs][0] + pj[bs][0];
        float zi = acc[bs][1] + pj[bs][1];
        float zf = acc[bs][2] + pj[bs][2];
        float zo = acc[bs][3] + pj[bs][3];
        float gg = tanh_fast(zg);
        float ii = sigf(zi);
        float ff = sigf(zf);
        float oo = sigf(zo);
        float cn = gg * ii + cv[bs] * ff;
        cv[bs] = cn;
        hnv[bs] = tanh_fast(cn) * oo;
    }
    *(f32x4*)cp = cv;

    // pure-register wave transpose via shfl (verified r6-r8 pattern)
    unsigned plo = (unsigned)f2bf(hnv[0]) | ((unsigned)f2bf(hnv[1]) << 16);
    unsigned phi = (unsigned)f2bf(hnv[2]) | ((unsigned)f2bf(hnv[3]) << 16);
    unsigned short o4[4];
#pragma unroll
    for (int p = 0; p < 4; p++) {
        int src = p * 16 + l15;
        unsigned vlo = __shfl(plo, src);
        unsigned vhi = __shfl(phi, src);
        unsigned sel = (l4 < 2) ? vlo : vhi;
        o4[p] = (l4 & 1) ? (unsigned short)(sel >> 16) : (unsigned short)(sel & 0xffffu);
    }
    u64 hv = (u64)o4[0] | ((u64)o4[1] << 16) | ((u64)o4[2] << 32) | ((u64)o4[3] << 48);
    __hip_bfloat16* hw = hbuf + (size_t)((t + 1) & 1) * 2 * B * H + dBH
                         + (size_t)(b0 + lane) * H + jt * 32 + wid * 4;
    *(u64a*)hw = hv;
}

// ---- head: logits + log_softmax (reads bf16 h, parity 0) ----
__global__ void head_kernel(const __hip_bfloat16* __restrict__ hbuf,
                            const float* __restrict__ p_w,
                            const float* __restrict__ p_b,
                            float* __restrict__ out) {
    int b = blockIdx.x;
    int lane = threadIdx.x;  // 64
    float part[C];
#pragma unroll
    for (int cc = 0; cc < C; cc++) part[cc] = 0.0f;
    for (int jj = lane; jj < 2 * H; jj += 64) {
        float hv = (jj < H)
            ? __bfloat162float(hbuf[(size_t)b * H + jj])
            : __bfloat162float(hbuf[(size_t)B * H + (size_t)b * H + jj - H]);
#pragma unroll
        for (int cc = 0; cc < C; cc++) part[cc] += hv * p_w[cc * 2 * H + jj];
    }
#pragma unroll
    for (int cc = 0; cc < C; cc++) {
        float v = part[cc];
        for (int off = 32; off; off >>= 1) v += __shfl_down(v, off);
        part[cc] = v;
    }
    if (lane == 0) {
        float lg[C];
        float m = -1e30f;
        for (int cc = 0; cc < C; cc++) {
            lg[cc] = part[cc] + p_b[cc];
            m = fmaxf(m, lg[cc]);
        }
        float s = 0.0f;
        for (int cc = 0; cc < C; cc++) s += expf(lg[cc] - m);
        float lse = logf(s) + m;
        for (int cc = 0; cc < C; cc++) out[b * C + cc] = lg[cc] - lse;
    }
}

extern "C" void kernel_launch(void* const* d_in, const int* in_sizes, int n_in,
                              void* d_out, int out_size, void* d_ws, size_t ws_size,
                              hipStream_t stream) {
    const int*   x     = (const int*)d_in[0];
    const float* embed = (const float*)d_in[1];
    const float* fwd_W = (const float*)d_in[2];
    const float* fwd_b = (const float*)d_in[3];
    const float* bwd_W = (const float*)d_in[4];
    const float* bwd_b = (const float*)d_in[5];
    const float* p_w   = (const float*)d_in[6];
    const float* p_b   = (const float*)d_in[7];
    float* outp = (float*)d_out;

    char* ws = (char*)d_ws;
    __hip_bfloat16* wF  = (__hip_bfloat16*)ws;  ws += (size_t)2 * 256 * 16384 * 2;    // 16 MB
    // 8 MB region shared in time: wxF (prep only) overlays cws (steps only)
    __hip_bfloat16* wxF = (__hip_bfloat16*)ws;
    float* cws = (float*)ws;                    ws += (size_t)2 * 256 * 8192 * 2;     // 8 MB
    unsigned short* ehl = (unsigned short*)ws;  ws += (size_t)2 * 128 * 512 * 2;      // 256 KB
    float* projP = (float*)ws;                  ws += (size_t)2 * 1024 * 128 * 4 * 4; // 4 MB
    __hip_bfloat16* hbuf = (__hip_bfloat16*)ws; ws += (size_t)2 * 2 * B * H * 2;      // 2 MB

    hipLaunchKernelGGL(wf_build, dim3(4096), dim3(256), 0, stream, fwd_W, bwd_W, wF);
    hipLaunchKernelGGL(wxf_build, dim3(2048), dim3(256), 0, stream, fwd_W, bwd_W, wxF);
    hipLaunchKernelGGL(ehl_build, dim3(256), dim3(256), 0, stream, embed, ehl);

    hipFuncSetAttribute((const void*)projp_mfma,
                        hipFuncAttributeMaxDynamicSharedMemorySize, 65536);
    hipLaunchKernelGGL(projp_mfma, dim3(256), dim3(256), 65536, stream,
                       wxF, ehl, fwd_b, bwd_b, projP);

    hipFuncSetAttribute((const void*)step_kernel,
                        hipFuncAttributeMaxDynamicSharedMemorySize, LDS_H);
    for (int t = 0; t < S; t++)
        hipLaunchKernelGGL(step_kernel, dim3(256), dim3(512), LDS_H, stream,
                           x, wF, projP, hbuf, cws, t);

    hipLaunchKernelGGL(head_kernel, dim3(B), dim3(64), 0, stream,
                       hbuf, p_w, p_b, outp);
}